// Round 7
// baseline (322.849 us; speedup 1.0000x reference)
//
#include <hip/hip_runtime.h>
#include <hip/hip_bf16.h>
#include <cstdint>
#include <math.h>

#define B_DIM 32
#define T_DIM 1000
#define D_DIM 768
#define V_DIM 31
#define L_DIM 200
#define S_DIM 401      // 2L+1 CTC states
#define SP 7           // states per lane (64*7 = 448 >= 401)
#define S_PAD 448
#define VSTRIDE 32     // padded prob-row stride: 32 floats = 128 B

// Wave-wide shift-up-by-1 via DPP WAVE_SHR1 (0x138): pure VALU. Lane 0 -> 0.
__device__ __forceinline__ float shup1_f(float x) {
    int r = __builtin_amdgcn_update_dpp(0, __float_as_int(x), 0x138, 0xF, 0xF, true);
    return __int_as_float(r);
}
__device__ __forceinline__ int shup1_i(int x) {
    return __builtin_amdgcn_update_dpp(0, x, 0x138, 0xF, 0xF, true);
}

// ---------------------------------------------------------------------------
// Kernel 1: logits = pred @ W^T + b, probs = softmax -> ws (B,T,32), linear.
// W comes over the SCALAR pipe (wave-uniform s_load + v_fmac s-operand) so
// the DS pipe is not the bottleneck. Wave pair (kh=0/1) splits K 2x384;
// kh=1 waves dump partials to LDS, kh=0 waves merge + softmax + store.
// Block 256 = 4 waves covers 128 rows; grid 250 (~1 block/CU, 1 wave/SIMD).
// ---------------------------------------------------------------------------
__global__ __launch_bounds__(256) void head_softmax_kernel(
    const float* __restrict__ pred,
    const float* __restrict__ W,
    const float* __restrict__ bias,
    float* __restrict__ probs)
{
    __shared__ float partH[128][V_DIM];      // kh=1 partial sums (15.9 KB)
    const int tid  = threadIdx.x;
    const int lane = tid & 63;
    const int kh   = __builtin_amdgcn_readfirstlane((tid >> 6) & 1);  // K half
    const int wg   = __builtin_amdgcn_readfirstlane(tid >> 7);        // row group
    const int rloc = wg * 64 + lane;                                  // 0..127
    const int row  = blockIdx.x * 128 + rloc;   // grid = 32000/128 = 250 exactly

    const float* pr = pred + (size_t)row * D_DIM + kh * 384;
    const float* wb = W + kh * 384;             // wave-uniform -> s_load

    float acc[V_DIM];
#pragma unroll
    for (int v = 0; v < V_DIM; ++v) acc[v] = 0.f;

    for (int kt = 0; kt < 384; kt += 32) {      // k-tile: W tile 4 KB stays hot
#pragma unroll
        for (int k = 0; k < 32; k += 4) {
            const float4 x = *reinterpret_cast<const float4*>(pr + kt + k);
#pragma unroll
            for (int v = 0; v < V_DIM; ++v) {
                const float* wp = wb + v * D_DIM + kt + k;   // uniform -> s_load
                acc[v] = fmaf(x.x, wp[0], acc[v]);
                acc[v] = fmaf(x.y, wp[1], acc[v]);
                acc[v] = fmaf(x.z, wp[2], acc[v]);
                acc[v] = fmaf(x.w, wp[3], acc[v]);
            }
        }
    }

    if (kh == 1) {
#pragma unroll
        for (int v = 0; v < V_DIM; ++v) partH[rloc][v] = acc[v];
    }
    __syncthreads();

    if (kh == 0) {
        float lg[V_DIM];
        float m = -1e30f;
#pragma unroll
        for (int v = 0; v < V_DIM; ++v) {
            lg[v] = acc[v] + partH[rloc][v] + bias[v];
            m = fmaxf(m, lg[v]);
        }
        float e[32];
        float s = 0.f;
#pragma unroll
        for (int v = 0; v < V_DIM; ++v) { e[v] = __expf(lg[v] - m); s += e[v]; }
        const float inv = 1.0f / s;
#pragma unroll
        for (int v = 0; v < V_DIM; ++v) e[v] *= inv;
        e[31] = 0.f;
        float* op = probs + (size_t)row * VSTRIDE;
#pragma unroll
        for (int q = 0; q < 8; ++q)
            *reinterpret_cast<float4*>(op + q * 4) =
                *reinterpret_cast<float4*>(&e[q * 4]);
    }
}

// ---------------------------------------------------------------------------
// Kernel 2: CTC forward recursion, linear domain, per-lane pow2 scaling
// (renorm every 2 steps, exact). probs rows staged into LDS via
// global_load_lds DMA (zero VGPR cost), 16-step chunks, 2-chunk lookahead,
// counted s_waitcnt vmcnt(8). One wave per batch element.
// ---------------------------------------------------------------------------
__global__ __launch_bounds__(64, 1) void ctc_alpha_kernel(
    const float* __restrict__ probs,
    const int* __restrict__ targets,
    const int* __restrict__ in_lens,
    const int* __restrict__ tgt_lens,
    float* __restrict__ out_nll)
{
    __shared__ float lbuf[2][16][VSTRIDE];   // 4 KB staging (2 chunks x 16 rows)
    __shared__ float sal[S_PAD];

    const int b    = blockIdx.x;
    const int lane = threadIdx.x;
    const int Tin  = in_lens[b];
    const int tl   = tgt_lens[b];
    const int* tgt = targets + b * L_DIM;
    const float* __restrict__ prow = probs + (size_t)b * T_DIM * VSTRIDE;

    int   eoff[SP];
    float m2[SP];
#pragma unroll
    for (int i = 0; i < SP; ++i) {
        const int s = lane * SP + i;
        int e = 0;
        float mm = 0.f;
        if (s < S_DIM && (s & 1)) {
            const int k = (s - 1) >> 1;
            const int lab = tgt[k];
            e = lab;
            if (s >= 3 && lab != tgt[k - 1]) mm = 1.f;
        }
        eoff[i] = e;
        m2[i]   = mm;
    }

    // t=0 init
    float a[SP];
#pragma unroll
    for (int i = 0; i < SP; ++i) a[i] = 0.f;
    if (lane == 0) {
        a[0] = prow[0];
        a[1] = prow[eoff[1]];
    }
    int   z2 = 0;
    float f  = (lane == 0) ? 0.f : 1.0f;

    // DMA one 16-row chunk (8 instrs, 2 rows each) into lbuf[buf]
    auto ISSUE = [&](int buf, int tbase) {
#pragma unroll
        for (int i = 0; i < 8; ++i) {
            int rowb = tbase + 2 * i;
            if (rowb > T_DIM - 2) rowb = T_DIM - 2;   // clamp, stays in-bounds
            const float* src = prow + (size_t)rowb * VSTRIDE + lane;
            float* dst = &lbuf[buf][2 * i][0];        // wave-uniform base
            __builtin_amdgcn_global_load_lds(
                (const __attribute__((address_space(1))) void*)src,
                (__attribute__((address_space(3))) void*)dst, 4, 0, 0);
        }
    };

    auto STEPP = [&](const float* rp) {
        float pp[SP];
#pragma unroll
        for (int i = 0; i < SP; ++i) pp[i] = rp[eoff[i]];   // ds_read_b32
        const float a6  = shup1_f(a[SP - 1]);   // DPP: lane0 -> 0
        const float a5  = shup1_f(a[SP - 2]);
        const float am1 = a6 * f;
        const float am2 = a5 * f;
        float nw[SP];
        nw[0] = (a[0] + am1  + m2[0] * am2) * pp[0];
        nw[1] = (a[1] + a[0] + m2[1] * am1) * pp[1];
#pragma unroll
        for (int i = 2; i < SP; ++i)
            nw[i] = (a[i] + a[i - 1] + m2[i] * a[i - 2]) * pp[i];
#pragma unroll
        for (int i = 0; i < SP; ++i) a[i] = nw[i];
    };

    auto RENORM = [&]() {
        const float mx = fmaxf(fmaxf(fmaxf(a[0], a[1]), fmaxf(a[2], a[3])),
                               fmaxf(fmaxf(a[4], a[5]), a[6]));
        int e;
        (void)frexpf(mx, &e);                    // mx==0 -> e=0
        const int zc = z2 + e;
        const int zp = shup1_i(zc);
        z2 = (mx > 0.f) ? zc : ((lane == 0) ? zc : zp);
#pragma unroll
        for (int i = 0; i < SP; ++i) a[i] = ldexpf(a[i], -e);
        int dz = zp - z2;
        if (dz > 126) dz = 126;
        if (dz < -126) dz = -126;
        f = (lane == 0) ? 0.f : ldexpf(1.0f, dz);
    };

#define PAIR(bf, j0) STEPP(&lbuf[bf][j0][0]); STEPP(&lbuf[bf][j0 + 1][0]); RENORM();
#define CHUNK16(bf) PAIR(bf,0) PAIR(bf,2) PAIR(bf,4) PAIR(bf,6) \
                    PAIR(bf,8) PAIR(bf,10) PAIR(bf,12) PAIR(bf,14)

    ISSUE(0, 1);            // chunk 0: rows 1..16
    ISSUE(1, 17);           // chunk 1: rows 17..32
    int tb = 1;
    int cur = 0;
    while (tb + 16 <= Tin) {
        asm volatile("s_waitcnt vmcnt(8)" ::: "memory");  // current chunk ready
        if (cur == 0) { CHUNK16(0); ISSUE(0, tb + 32); }
        else          { CHUNK16(1); ISSUE(1, tb + 32); }
        tb += 16;
        cur ^= 1;
    }
    asm volatile("s_waitcnt vmcnt(0)" ::: "memory");      // tail chunk ready
    const int rem = Tin - tb;                              // 0..15
    {
        const float* tp = &lbuf[cur][0][0];
        if (rem >  0) STEPP(tp +  0 * VSTRIDE);
        if (rem >  1) STEPP(tp +  1 * VSTRIDE);
        RENORM();
        if (rem >  2) STEPP(tp +  2 * VSTRIDE);
        if (rem >  3) STEPP(tp +  3 * VSTRIDE);
        RENORM();
        if (rem >  4) STEPP(tp +  4 * VSTRIDE);
        if (rem >  5) STEPP(tp +  5 * VSTRIDE);
        RENORM();
        if (rem >  6) STEPP(tp +  6 * VSTRIDE);
        if (rem >  7) STEPP(tp +  7 * VSTRIDE);
        RENORM();
        if (rem >  8) STEPP(tp +  8 * VSTRIDE);
        if (rem >  9) STEPP(tp +  9 * VSTRIDE);
        RENORM();
        if (rem > 10) STEPP(tp + 10 * VSTRIDE);
        if (rem > 11) STEPP(tp + 11 * VSTRIDE);
        RENORM();
        if (rem > 12) STEPP(tp + 12 * VSTRIDE);
        if (rem > 13) STEPP(tp + 13 * VSTRIDE);
        RENORM();
        if (rem > 14) STEPP(tp + 14 * VSTRIDE);
    }

    // absolute log-alpha: log(a) + z2*ln2
    const float zln2 = (float)z2 * 0.69314718055994530942f;
#pragma unroll
    for (int i = 0; i < SP; ++i) sal[lane * SP + i] = __logf(a[i]) + zln2;
    __syncthreads();
    if (lane == 0) {
        const float a0 = sal[2 * tl - 1];
        const float a1 = sal[2 * tl];
        const float m  = fmaxf(a0, a1);
        float nll = -(m + __logf(__expf(a0 - m) + __expf(a1 - m)));
        if (!(nll < 1e29f)) nll = 0.f;           // zero_infinity (inf/NaN too)
        out_nll[b] = nll / (float)tl;
    }
}

// ---------------------------------------------------------------------------
// Kernel 3: deterministic mean over B
// ---------------------------------------------------------------------------
__global__ void finalize_kernel(const float* __restrict__ nll, float* __restrict__ out)
{
    if (threadIdx.x == 0 && blockIdx.x == 0) {
        float s = 0.f;
        for (int i = 0; i < B_DIM; ++i) s += nll[i];
        out[0] = s * (1.0f / (float)B_DIM);
    }
}

extern "C" void kernel_launch(void* const* d_in, const int* in_sizes, int n_in,
                              void* d_out, int out_size, void* d_ws, size_t ws_size,
                              hipStream_t stream)
{
    const float* pred     = (const float*)d_in[0];
    const int*   targets  = (const int*)d_in[1];
    const int*   in_lens  = (const int*)d_in[2];
    const int*   tgt_lens = (const int*)d_in[3];
    const float* W        = (const float*)d_in[4];
    const float* bias     = (const float*)d_in[5];

    float* probs = (float*)d_ws;                                  // 32*1000*32 f32 = 4.1 MB
    float* nll   = probs + (size_t)B_DIM * T_DIM * VSTRIDE;       // 32 f32
    float* out   = (float*)d_out;

    head_softmax_kernel<<<(B_DIM * T_DIM) / 128, 256, 0, stream>>>(pred, W, bias, probs);
    ctc_alpha_kernel<<<B_DIM, 64, 0, stream>>>(probs, targets, in_lens, tgt_lens, nll);
    finalize_kernel<<<1, 64, 0, stream>>>(nll, out);
}

// Round 8
// 137.339 us; speedup vs baseline: 2.3508x; 2.3508x over previous
//
#include <hip/hip_runtime.h>
#include <hip/hip_bf16.h>
#include <cstdint>
#include <math.h>

#define B_DIM 32
#define T_DIM 1000
#define D_DIM 768
#define V_DIM 31
#define L_DIM 200
#define S_DIM 401      // 2L+1 CTC states
#define SP 7           // states per lane (64*7 = 448 >= 401)
#define S_PAD 448
#define VSTRIDE 32     // padded prob-row stride: 32 floats = 128 B

typedef __bf16 bf16x8 __attribute__((ext_vector_type(8)));
typedef float  f32x16 __attribute__((ext_vector_type(16)));

// Wave-wide shift-up-by-1 via DPP WAVE_SHR1 (0x138): pure VALU. Lane 0 -> 0.
__device__ __forceinline__ float shup1_f(float x) {
    int r = __builtin_amdgcn_update_dpp(0, __float_as_int(x), 0x138, 0xF, 0xF, true);
    return __int_as_float(r);
}
__device__ __forceinline__ int shup1_i(int x) {
    return __builtin_amdgcn_update_dpp(0, x, 0x138, 0xF, 0xF, true);
}

// ---------------------------------------------------------------------------
// Kernel 1: logits = pred @ W^T + b via MFMA bf16, probs = softmax -> ws.
// Block = 256 (4 waves) covers 32 rows; waves K-split 4 x 192.
// mfma_f32_32x32x16_bf16: one 32x32 tile covers all 31 vocab cols.
// A: row = lane&31, k = 8*(lane>>5)+i.  C/D: col = lane&31,
// row = (reg&3) + 8*(reg>>2) + 4*(lane>>5)   [verified m74/m101].
// ---------------------------------------------------------------------------
__global__ __launch_bounds__(256) void head_softmax_kernel(
    const float* __restrict__ pred,
    const float* __restrict__ W,
    const float* __restrict__ bias,
    float* __restrict__ probs)
{
    __shared__ float red[3][64][16];   // waves 1..3 partial C tiles (12 KB)
    __shared__ float sm2[32][33];      // transpose pad 33 -> conflict-free
    const int tid  = threadIdx.x;
    const int lane = tid & 63;
    const int w    = __builtin_amdgcn_readfirstlane(tid >> 6);  // K segment
    const int col  = lane & 31;
    const int h    = lane >> 5;
    const int row  = blockIdx.x * 32 + col;     // grid = 1000 exactly
    const int vc   = (col < V_DIM) ? col : (V_DIM - 1);  // clamp pad col

    const float* pA = pred + (size_t)row * D_DIM + w * 192 + 8 * h;
    const float* pB = W + (size_t)vc * D_DIM + w * 192 + 8 * h;

    f32x16 acc;
#pragma unroll
    for (int i = 0; i < 16; ++i) acc[i] = 0.f;

#pragma unroll
    for (int kt = 0; kt < 12; ++kt) {
        const float4 a0 = *reinterpret_cast<const float4*>(pA + kt * 16);
        const float4 a1 = *reinterpret_cast<const float4*>(pA + kt * 16 + 4);
        const float4 b0 = *reinterpret_cast<const float4*>(pB + kt * 16);
        const float4 b1 = *reinterpret_cast<const float4*>(pB + kt * 16 + 4);
        bf16x8 af, bfr;
        af[0] = (__bf16)a0.x; af[1] = (__bf16)a0.y;
        af[2] = (__bf16)a0.z; af[3] = (__bf16)a0.w;
        af[4] = (__bf16)a1.x; af[5] = (__bf16)a1.y;
        af[6] = (__bf16)a1.z; af[7] = (__bf16)a1.w;
        bfr[0] = (__bf16)b0.x; bfr[1] = (__bf16)b0.y;
        bfr[2] = (__bf16)b0.z; bfr[3] = (__bf16)b0.w;
        bfr[4] = (__bf16)b1.x; bfr[5] = (__bf16)b1.y;
        bfr[6] = (__bf16)b1.z; bfr[7] = (__bf16)b1.w;
        acc = __builtin_amdgcn_mfma_f32_32x32x16_bf16(af, bfr, acc, 0, 0, 0);
    }

    if (w > 0) {
#pragma unroll
        for (int q = 0; q < 4; ++q)
            *reinterpret_cast<float4*>(&red[w - 1][lane][q * 4]) =
                make_float4(acc[q * 4], acc[q * 4 + 1], acc[q * 4 + 2], acc[q * 4 + 3]);
    }
    __syncthreads();
    if (w == 0) {
#pragma unroll
        for (int i = 0; i < 16; ++i)
            acc[i] += red[0][lane][i] + red[1][lane][i] + red[2][lane][i];
        // transpose C to sm2[row][col] (intra-wave; DS ops are in-order)
#pragma unroll
        for (int r = 0; r < 16; ++r) {
            const int rl = (r & 3) + 8 * (r >> 2) + 4 * h;
            sm2[rl][col] = acc[r];
        }
        if (lane < 32) {
            float lg[V_DIM];
            float m = -1e30f;
#pragma unroll
            for (int v = 0; v < V_DIM; ++v) {
                lg[v] = sm2[lane][v] + bias[v];
                m = fmaxf(m, lg[v]);
            }
            float e[32];
            float s = 0.f;
#pragma unroll
            for (int v = 0; v < V_DIM; ++v) { e[v] = __expf(lg[v] - m); s += e[v]; }
            const float inv = 1.0f / s;
#pragma unroll
            for (int v = 0; v < V_DIM; ++v) e[v] *= inv;
            e[31] = 0.f;
            float* op = probs + (size_t)(blockIdx.x * 32 + lane) * VSTRIDE;
#pragma unroll
            for (int q = 0; q < 8; ++q)
                *reinterpret_cast<float4*>(op + q * 4) =
                    *reinterpret_cast<float4*>(&e[q * 4]);
        }
    }
}

// ---------------------------------------------------------------------------
// Kernel 2: CTC forward recursion (unchanged from round 7: linear domain,
// pow2 renorm every 2 steps, global_load_lds staging, counted vmcnt).
// ---------------------------------------------------------------------------
__global__ __launch_bounds__(64, 1) void ctc_alpha_kernel(
    const float* __restrict__ probs,
    const int* __restrict__ targets,
    const int* __restrict__ in_lens,
    const int* __restrict__ tgt_lens,
    float* __restrict__ out_nll)
{
    __shared__ float lbuf[2][16][VSTRIDE];   // 4 KB staging (2 chunks x 16 rows)
    __shared__ float sal[S_PAD];

    const int b    = blockIdx.x;
    const int lane = threadIdx.x;
    const int Tin  = in_lens[b];
    const int tl   = tgt_lens[b];
    const int* tgt = targets + b * L_DIM;
    const float* __restrict__ prow = probs + (size_t)b * T_DIM * VSTRIDE;

    int   eoff[SP];
    float m2[SP];
#pragma unroll
    for (int i = 0; i < SP; ++i) {
        const int s = lane * SP + i;
        int e = 0;
        float mm = 0.f;
        if (s < S_DIM && (s & 1)) {
            const int k = (s - 1) >> 1;
            const int lab = tgt[k];
            e = lab;
            if (s >= 3 && lab != tgt[k - 1]) mm = 1.f;
        }
        eoff[i] = e;
        m2[i]   = mm;
    }

    // t=0 init
    float a[SP];
#pragma unroll
    for (int i = 0; i < SP; ++i) a[i] = 0.f;
    if (lane == 0) {
        a[0] = prow[0];
        a[1] = prow[eoff[1]];
    }
    int   z2 = 0;
    float f  = (lane == 0) ? 0.f : 1.0f;

    auto ISSUE = [&](int buf, int tbase) {
#pragma unroll
        for (int i = 0; i < 8; ++i) {
            int rowb = tbase + 2 * i;
            if (rowb > T_DIM - 2) rowb = T_DIM - 2;   // clamp, stays in-bounds
            const float* src = prow + (size_t)rowb * VSTRIDE + lane;
            float* dst = &lbuf[buf][2 * i][0];        // wave-uniform base
            __builtin_amdgcn_global_load_lds(
                (const __attribute__((address_space(1))) void*)src,
                (__attribute__((address_space(3))) void*)dst, 4, 0, 0);
        }
    };

    auto STEPP = [&](const float* rp) {
        float pp[SP];
#pragma unroll
        for (int i = 0; i < SP; ++i) pp[i] = rp[eoff[i]];   // ds_read_b32
        const float a6  = shup1_f(a[SP - 1]);   // DPP: lane0 -> 0
        const float a5  = shup1_f(a[SP - 2]);
        const float am1 = a6 * f;
        const float am2 = a5 * f;
        float nw[SP];
        nw[0] = (a[0] + am1  + m2[0] * am2) * pp[0];
        nw[1] = (a[1] + a[0] + m2[1] * am1) * pp[1];
#pragma unroll
        for (int i = 2; i < SP; ++i)
            nw[i] = (a[i] + a[i - 1] + m2[i] * a[i - 2]) * pp[i];
#pragma unroll
        for (int i = 0; i < SP; ++i) a[i] = nw[i];
    };

    auto RENORM = [&]() {
        const float mx = fmaxf(fmaxf(fmaxf(a[0], a[1]), fmaxf(a[2], a[3])),
                               fmaxf(fmaxf(a[4], a[5]), a[6]));
        int e;
        (void)frexpf(mx, &e);                    // mx==0 -> e=0
        const int zc = z2 + e;
        const int zp = shup1_i(zc);
        z2 = (mx > 0.f) ? zc : ((lane == 0) ? zc : zp);
#pragma unroll
        for (int i = 0; i < SP; ++i) a[i] = ldexpf(a[i], -e);
        int dz = zp - z2;
        if (dz > 126) dz = 126;
        if (dz < -126) dz = -126;
        f = (lane == 0) ? 0.f : ldexpf(1.0f, dz);
    };

#define PAIR(bf, j0) STEPP(&lbuf[bf][j0][0]); STEPP(&lbuf[bf][j0 + 1][0]); RENORM();
#define CHUNK16(bf) PAIR(bf,0) PAIR(bf,2) PAIR(bf,4) PAIR(bf,6) \
                    PAIR(bf,8) PAIR(bf,10) PAIR(bf,12) PAIR(bf,14)

    ISSUE(0, 1);            // chunk 0: rows 1..16
    ISSUE(1, 17);           // chunk 1: rows 17..32
    int tb = 1;
    int cur = 0;
    while (tb + 16 <= Tin) {
        asm volatile("s_waitcnt vmcnt(8)" ::: "memory");  // current chunk ready
        if (cur == 0) { CHUNK16(0); ISSUE(0, tb + 32); }
        else          { CHUNK16(1); ISSUE(1, tb + 32); }
        tb += 16;
        cur ^= 1;
    }
    asm volatile("s_waitcnt vmcnt(0)" ::: "memory");      // tail chunk ready
    const int rem = Tin - tb;                              // 0..15
    {
        const float* tp = &lbuf[cur][0][0];
        if (rem >  0) STEPP(tp +  0 * VSTRIDE);
        if (rem >  1) STEPP(tp +  1 * VSTRIDE);
        RENORM();
        if (rem >  2) STEPP(tp +  2 * VSTRIDE);
        if (rem >  3) STEPP(tp +  3 * VSTRIDE);
        RENORM();
        if (rem >  4) STEPP(tp +  4 * VSTRIDE);
        if (rem >  5) STEPP(tp +  5 * VSTRIDE);
        RENORM();
        if (rem >  6) STEPP(tp +  6 * VSTRIDE);
        if (rem >  7) STEPP(tp +  7 * VSTRIDE);
        RENORM();
        if (rem >  8) STEPP(tp +  8 * VSTRIDE);
        if (rem >  9) STEPP(tp +  9 * VSTRIDE);
        RENORM();
        if (rem > 10) STEPP(tp + 10 * VSTRIDE);
        if (rem > 11) STEPP(tp + 11 * VSTRIDE);
        RENORM();
        if (rem > 12) STEPP(tp + 12 * VSTRIDE);
        if (rem > 13) STEPP(tp + 13 * VSTRIDE);
        RENORM();
        if (rem > 14) STEPP(tp + 14 * VSTRIDE);
    }

    // absolute log-alpha: log(a) + z2*ln2
    const float zln2 = (float)z2 * 0.69314718055994530942f;
#pragma unroll
    for (int i = 0; i < SP; ++i) sal[lane * SP + i] = __logf(a[i]) + zln2;
    __syncthreads();
    if (lane == 0) {
        const float a0 = sal[2 * tl - 1];
        const float a1 = sal[2 * tl];
        const float m  = fmaxf(a0, a1);
        float nll = -(m + __logf(__expf(a0 - m) + __expf(a1 - m)));
        if (!(nll < 1e29f)) nll = 0.f;           // zero_infinity (inf/NaN too)
        out_nll[b] = nll / (float)tl;
    }
}

// ---------------------------------------------------------------------------
// Kernel 3: deterministic mean over B
// ---------------------------------------------------------------------------
__global__ void finalize_kernel(const float* __restrict__ nll, float* __restrict__ out)
{
    if (threadIdx.x == 0 && blockIdx.x == 0) {
        float s = 0.f;
        for (int i = 0; i < B_DIM; ++i) s += nll[i];
        out[0] = s * (1.0f / (float)B_DIM);
    }
}

extern "C" void kernel_launch(void* const* d_in, const int* in_sizes, int n_in,
                              void* d_out, int out_size, void* d_ws, size_t ws_size,
                              hipStream_t stream)
{
    const float* pred     = (const float*)d_in[0];
    const int*   targets  = (const int*)d_in[1];
    const int*   in_lens  = (const int*)d_in[2];
    const int*   tgt_lens = (const int*)d_in[3];
    const float* W        = (const float*)d_in[4];
    const float* bias     = (const float*)d_in[5];

    float* probs = (float*)d_ws;                                  // 32*1000*32 f32 = 4.1 MB
    float* nll   = probs + (size_t)B_DIM * T_DIM * VSTRIDE;       // 32 f32
    float* out   = (float*)d_out;

    head_softmax_kernel<<<(B_DIM * T_DIM) / 32, 256, 0, stream>>>(pred, W, bias, probs);
    ctc_alpha_kernel<<<B_DIM, 64, 0, stream>>>(probs, targets, in_lens, tgt_lens, nll);
    finalize_kernel<<<1, 64, 0, stream>>>(nll, out);
}

// Round 9
// 129.311 us; speedup vs baseline: 2.4967x; 1.0621x over previous
//
#include <hip/hip_runtime.h>
#include <hip/hip_bf16.h>
#include <cstdint>
#include <math.h>

#define B_DIM 32
#define T_DIM 1000
#define D_DIM 768
#define V_DIM 31
#define L_DIM 200
#define S_DIM 401      // 2L+1 CTC states
#define SP 7           // states per lane (64*7 = 448 >= 401)
#define S_PAD 448
#define VSTRIDE 32     // padded prob-row stride: 32 floats = 128 B

typedef __bf16 bf16x8 __attribute__((ext_vector_type(8)));
typedef float  f32x16 __attribute__((ext_vector_type(16)));

// Wave-wide shift-up-by-1 via DPP WAVE_SHR1 (0x138): pure VALU. Lane 0 -> 0.
__device__ __forceinline__ float shup1_f(float x) {
    int r = __builtin_amdgcn_update_dpp(0, __float_as_int(x), 0x138, 0xF, 0xF, true);
    return __int_as_float(r);
}
__device__ __forceinline__ int shup1_i(int x) {
    return __builtin_amdgcn_update_dpp(0, x, 0x138, 0xF, 0xF, true);
}

// ---------------------------------------------------------------------------
// Kernel 1: logits = pred @ W^T + b via MFMA bf16, probs = softmax -> ws.
// (Unchanged from round 8: ~29 us, near HBM floor.)
// ---------------------------------------------------------------------------
__global__ __launch_bounds__(256) void head_softmax_kernel(
    const float* __restrict__ pred,
    const float* __restrict__ W,
    const float* __restrict__ bias,
    float* __restrict__ probs)
{
    __shared__ float red[3][64][16];   // waves 1..3 partial C tiles (12 KB)
    __shared__ float sm2[32][33];      // transpose pad 33 -> conflict-free
    const int tid  = threadIdx.x;
    const int lane = tid & 63;
    const int w    = __builtin_amdgcn_readfirstlane(tid >> 6);  // K segment
    const int col  = lane & 31;
    const int h    = lane >> 5;
    const int row  = blockIdx.x * 32 + col;     // grid = 1000 exactly
    const int vc   = (col < V_DIM) ? col : (V_DIM - 1);  // clamp pad col

    const float* pA = pred + (size_t)row * D_DIM + w * 192 + 8 * h;
    const float* pB = W + (size_t)vc * D_DIM + w * 192 + 8 * h;

    f32x16 acc;
#pragma unroll
    for (int i = 0; i < 16; ++i) acc[i] = 0.f;

#pragma unroll
    for (int kt = 0; kt < 12; ++kt) {
        const float4 a0 = *reinterpret_cast<const float4*>(pA + kt * 16);
        const float4 a1 = *reinterpret_cast<const float4*>(pA + kt * 16 + 4);
        const float4 b0 = *reinterpret_cast<const float4*>(pB + kt * 16);
        const float4 b1 = *reinterpret_cast<const float4*>(pB + kt * 16 + 4);
        bf16x8 af, bfr;
        af[0] = (__bf16)a0.x; af[1] = (__bf16)a0.y;
        af[2] = (__bf16)a0.z; af[3] = (__bf16)a0.w;
        af[4] = (__bf16)a1.x; af[5] = (__bf16)a1.y;
        af[6] = (__bf16)a1.z; af[7] = (__bf16)a1.w;
        bfr[0] = (__bf16)b0.x; bfr[1] = (__bf16)b0.y;
        bfr[2] = (__bf16)b0.z; bfr[3] = (__bf16)b0.w;
        bfr[4] = (__bf16)b1.x; bfr[5] = (__bf16)b1.y;
        bfr[6] = (__bf16)b1.z; bfr[7] = (__bf16)b1.w;
        acc = __builtin_amdgcn_mfma_f32_32x32x16_bf16(af, bfr, acc, 0, 0, 0);
    }

    if (w > 0) {
#pragma unroll
        for (int q = 0; q < 4; ++q)
            *reinterpret_cast<float4*>(&red[w - 1][lane][q * 4]) =
                make_float4(acc[q * 4], acc[q * 4 + 1], acc[q * 4 + 2], acc[q * 4 + 3]);
    }
    __syncthreads();
    if (w == 0) {
#pragma unroll
        for (int i = 0; i < 16; ++i)
            acc[i] += red[0][lane][i] + red[1][lane][i] + red[2][lane][i];
#pragma unroll
        for (int r = 0; r < 16; ++r) {
            const int rl = (r & 3) + 8 * (r >> 2) + 4 * h;
            sm2[rl][col] = acc[r];
        }
        if (lane < 32) {
            float lg[V_DIM];
            float m = -1e30f;
#pragma unroll
            for (int v = 0; v < V_DIM; ++v) {
                lg[v] = sm2[lane][v] + bias[v];
                m = fmaxf(m, lg[v]);
            }
            float e[32];
            float s = 0.f;
#pragma unroll
            for (int v = 0; v < V_DIM; ++v) { e[v] = __expf(lg[v] - m); s += e[v]; }
            const float inv = 1.0f / s;
#pragma unroll
            for (int v = 0; v < V_DIM; ++v) e[v] *= inv;
            e[31] = 0.f;
            float* op = probs + (size_t)(blockIdx.x * 32 + lane) * VSTRIDE;
#pragma unroll
            for (int q = 0; q < 8; ++q)
                *reinterpret_cast<float4*>(op + q * 4) =
                    *reinterpret_cast<float4*>(&e[q * 4]);
        }
    }
}

// ---------------------------------------------------------------------------
// Kernel 2: CTC forward recursion, linear domain, pow2 renorm every 2 steps.
// global_load_lds DMA staging + counted vmcnt (unchanged) PLUS a one-row
// register pipeline: row j+1's gathered probs are ds_read into ppn BEFORE
// computing step j from pp, so LDS latency hides under the step's VALU.
// ---------------------------------------------------------------------------
__global__ __launch_bounds__(64, 1) void ctc_alpha_kernel(
    const float* __restrict__ probs,
    const int* __restrict__ targets,
    const int* __restrict__ in_lens,
    const int* __restrict__ tgt_lens,
    float* __restrict__ out_nll)
{
    __shared__ float lbuf[2][16][VSTRIDE];   // 4 KB staging (2 chunks x 16 rows)
    __shared__ float sal[S_PAD];

    const int b    = blockIdx.x;
    const int lane = threadIdx.x;
    const int Tin  = in_lens[b];
    const int tl   = tgt_lens[b];
    const int* tgt = targets + b * L_DIM;
    const float* __restrict__ prow = probs + (size_t)b * T_DIM * VSTRIDE;

    int   eoff[SP];
    float m2[SP];
#pragma unroll
    for (int i = 0; i < SP; ++i) {
        const int s = lane * SP + i;
        int e = 0;
        float mm = 0.f;
        if (s < S_DIM && (s & 1)) {
            const int k = (s - 1) >> 1;
            const int lab = tgt[k];
            e = lab;
            if (s >= 3 && lab != tgt[k - 1]) mm = 1.f;
        }
        eoff[i] = e;
        m2[i]   = mm;
    }

    // t=0 init
    float a[SP];
#pragma unroll
    for (int i = 0; i < SP; ++i) a[i] = 0.f;
    if (lane == 0) {
        a[0] = prow[0];
        a[1] = prow[eoff[1]];
    }
    int   z2 = 0;
    float f  = (lane == 0) ? 0.f : 1.0f;

    auto ISSUE = [&](int buf, int tbase) {
#pragma unroll
        for (int i = 0; i < 8; ++i) {
            int rowb = tbase + 2 * i;
            if (rowb > T_DIM - 2) rowb = T_DIM - 2;   // clamp, stays in-bounds
            const float* src = prow + (size_t)rowb * VSTRIDE + lane;
            float* dst = &lbuf[buf][2 * i][0];        // wave-uniform base
            __builtin_amdgcn_global_load_lds(
                (const __attribute__((address_space(1))) void*)src,
                (__attribute__((address_space(3))) void*)dst, 4, 0, 0);
        }
    };

    float pp[SP], ppn[SP];
    auto RD = [&](int bf, int row) {     // gather row -> ppn (7 ds_read_b32)
#pragma unroll
        for (int i = 0; i < SP; ++i) ppn[i] = lbuf[bf][row][eoff[i]];
    };
    auto CPY = [&]() {
#pragma unroll
        for (int i = 0; i < SP; ++i) pp[i] = ppn[i];
    };

    auto STEPC = [&]() {                 // compute one step from pp (no reads)
        const float a6  = shup1_f(a[SP - 1]);   // DPP: lane0 -> 0
        const float a5  = shup1_f(a[SP - 2]);
        const float am1 = a6 * f;
        const float am2 = a5 * f;
        float nw[SP];
        nw[0] = (a[0] + am1  + m2[0] * am2) * pp[0];
        nw[1] = (a[1] + a[0] + m2[1] * am1) * pp[1];
#pragma unroll
        for (int i = 2; i < SP; ++i)
            nw[i] = (a[i] + a[i - 1] + m2[i] * a[i - 2]) * pp[i];
#pragma unroll
        for (int i = 0; i < SP; ++i) a[i] = nw[i];
    };

    auto RENORM = [&]() {
        const float mx = fmaxf(fmaxf(fmaxf(a[0], a[1]), fmaxf(a[2], a[3])),
                               fmaxf(fmaxf(a[4], a[5]), a[6]));
        int e;
        (void)frexpf(mx, &e);                    // mx==0 -> e=0
        const int zc = z2 + e;
        const int zp = shup1_i(zc);
        z2 = (mx > 0.f) ? zc : ((lane == 0) ? zc : zp);
#pragma unroll
        for (int i = 0; i < SP; ++i) a[i] = ldexpf(a[i], -e);
        int dz = zp - z2;
        if (dz > 126) dz = 126;
        if (dz < -126) dz = -126;
        f = (lane == 0) ? 0.f : ldexpf(1.0f, dz);
    };

    // pipelined 16-step chunk: prefetch row j+1, compute row j
    auto CHUNK = [&](int bf) {
#pragma unroll
        for (int j = 0; j < 15; ++j) {
            RD(bf, j + 1);
            STEPC();
            if (j & 1) RENORM();
            CPY();
        }
        STEPC();        // row 15
        RENORM();
    };

    ISSUE(0, 1);            // chunk 0: rows 1..16
    ISSUE(1, 17);           // chunk 1: rows 17..32
    asm volatile("s_waitcnt vmcnt(8)" ::: "memory");  // chunk 0 ready
    RD(0, 0); CPY();        // pp = first row of chunk 0

    int tb = 1;
    int cur = 0;
    while (tb + 16 <= Tin) {
        if (cur == 0) { CHUNK(0); ISSUE(0, tb + 32); }
        else          { CHUNK(1); ISSUE(1, tb + 32); }
        asm volatile("s_waitcnt vmcnt(8)" ::: "memory");  // next chunk ready
        RD(cur ^ 1, 0); CPY();                            // preload its row 0
        tb += 16;
        cur ^= 1;
    }

    // tail: rem <= 15 steps in buf cur; pp = row 0 already loaded
    const int rem = Tin - tb;
    if (rem >  0) { RD(cur,  1); STEPC();           CPY(); }
    if (rem >  1) { RD(cur,  2); STEPC(); RENORM(); CPY(); }
    if (rem >  2) { RD(cur,  3); STEPC();           CPY(); }
    if (rem >  3) { RD(cur,  4); STEPC(); RENORM(); CPY(); }
    if (rem >  4) { RD(cur,  5); STEPC();           CPY(); }
    if (rem >  5) { RD(cur,  6); STEPC(); RENORM(); CPY(); }
    if (rem >  6) { RD(cur,  7); STEPC();           CPY(); }
    if (rem >  7) { RD(cur,  8); STEPC(); RENORM(); CPY(); }
    if (rem >  8) { RD(cur,  9); STEPC();           CPY(); }
    if (rem >  9) { RD(cur, 10); STEPC(); RENORM(); CPY(); }
    if (rem > 10) { RD(cur, 11); STEPC();           CPY(); }
    if (rem > 11) { RD(cur, 12); STEPC(); RENORM(); CPY(); }
    if (rem > 12) { RD(cur, 13); STEPC();           CPY(); }
    if (rem > 13) { RD(cur, 14); STEPC(); RENORM(); CPY(); }
    if (rem > 14) { STEPC(); RENORM(); }

    // absolute log-alpha: log(a) + z2*ln2
    const float zln2 = (float)z2 * 0.69314718055994530942f;
#pragma unroll
    for (int i = 0; i < SP; ++i) sal[lane * SP + i] = __logf(a[i]) + zln2;
    __syncthreads();
    if (lane == 0) {
        const float a0 = sal[2 * tl - 1];
        const float a1 = sal[2 * tl];
        const float m  = fmaxf(a0, a1);
        float nll = -(m + __logf(__expf(a0 - m) + __expf(a1 - m)));
        if (!(nll < 1e29f)) nll = 0.f;           // zero_infinity (inf/NaN too)
        out_nll[b] = nll / (float)tl;
    }
}

// ---------------------------------------------------------------------------
// Kernel 3: deterministic mean over B
// ---------------------------------------------------------------------------
__global__ void finalize_kernel(const float* __restrict__ nll, float* __restrict__ out)
{
    if (threadIdx.x == 0 && blockIdx.x == 0) {
        float s = 0.f;
        for (int i = 0; i < B_DIM; ++i) s += nll[i];
        out[0] = s * (1.0f / (float)B_DIM);
    }
}

extern "C" void kernel_launch(void* const* d_in, const int* in_sizes, int n_in,
                              void* d_out, int out_size, void* d_ws, size_t ws_size,
                              hipStream_t stream)
{
    const float* pred     = (const float*)d_in[0];
    const int*   targets  = (const int*)d_in[1];
    const int*   in_lens  = (const int*)d_in[2];
    const int*   tgt_lens = (const int*)d_in[3];
    const float* W        = (const float*)d_in[4];
    const float* bias     = (const float*)d_in[5];

    float* probs = (float*)d_ws;                                  // 32*1000*32 f32 = 4.1 MB
    float* nll   = probs + (size_t)B_DIM * T_DIM * VSTRIDE;       // 32 f32
    float* out   = (float*)d_out;

    head_softmax_kernel<<<(B_DIM * T_DIM) / 32, 256, 0, stream>>>(pred, W, bias, probs);
    ctc_alpha_kernel<<<B_DIM, 64, 0, stream>>>(probs, targets, in_lens, tgt_lens, nll);
    finalize_kernel<<<1, 64, 0, stream>>>(nll, out);
}